// Round 6
// baseline (302.567 us; speedup 1.0000x reference)
//
#include <hip/hip_runtime.h>
#include <hip/hip_bf16.h>

#define NNODES 50000
#define NFEAT  128
#define NEDGES 600000
#define HID    256
#define HID2   128
#define LEAKY  0.01f

typedef __attribute__((ext_vector_type(8))) short short8;
typedef __attribute__((ext_vector_type(4))) float floatx4;

// Truncation split: x ~= hi + lo (each bf16), residual ~2^-17 rel.
__device__ __forceinline__ void split_bf16(float x, unsigned short& hi, unsigned short& lo) {
  union { float f; unsigned u; } a; a.f = x;
  hi = (unsigned short)(a.u >> 16);
  union { float f; unsigned u; } h; h.u = (unsigned)hi << 16;
  union { float f; unsigned u; } r; r.f = x - h.f;
  lo = (unsigned short)(r.u >> 16);
}

// RNE fp32 -> bf16 (scalar)
__device__ __forceinline__ unsigned short bf16_rne(float x) {
  union { float f; unsigned u; } a; a.f = x;
  unsigned r = a.u + 0x7FFFu + ((a.u >> 16) & 1u);
  return (unsigned short)(r >> 16);
}

// RNE pack two fp32 -> u32 of 2 bf16 (a in low half) — emits cvt_pk.
__device__ __forceinline__ unsigned pack2_rne(float a, float b) {
  __hip_bfloat162 h = __float22bfloat162_rn(make_float2(a, b));
  unsigned u; __builtin_memcpy(&u, &h, 4); return u;
}

__device__ __forceinline__ float ubits2f(unsigned u) {
  union { unsigned u; float f; } c; c.u = u; return c.f;
}

// relu(P+Q) for a packed bf16 pair (b1 pre-folded into P), repacked RNE.
__device__ __forceinline__ unsigned fuse2(unsigned pw, unsigned qw) {
  const float a0 = ubits2f(pw << 16), a1 = ubits2f(pw & 0xFFFF0000u);
  const float c0 = ubits2f(qw << 16), c1 = ubits2f(qw & 0xFFFF0000u);
  return pack2_rne(fmaxf(a0 + c0, 0.f), fmaxf(a1 + c1, 0.f));
}

// ---------------------------------------------------------------------------
// pack_w: merged W2 + W1 packing into MFMA B-frag order, bf16 hi/lo planes.
// W2F[((ks*8+nf)*64+l)*8+i]:  k=ks*32+(l>>4)*8+i, col=nf*16+(l&15)   (32768/plane)
// W1F[((ks*32+nf)*64+l)*8+i]: k=ks*32+(l>>4)*8+i, n=nf*16+(l&15)     (65536/plane)
//   W1'[k][n] = n<256 ? W1[k][n] : W1[128+k][n-256]
// ---------------------------------------------------------------------------
__global__ __launch_bounds__(256) void pack_w(const float* __restrict__ W2,
                                              const float* __restrict__ W1,
                                              unsigned short* __restrict__ W2F,
                                              unsigned short* __restrict__ W1F) {
  const int gid = blockIdx.x * 256 + threadIdx.x;
  if (gid < 32768) {
    const int idx = gid;
    const int i  = idx & 7;
    const int l  = (idx >> 3) & 63;
    const int nf = (idx >> 9) & 7;
    const int ks = idx >> 12;
    const int k   = ks * 32 + (l >> 4) * 8 + i;
    const int col = nf * 16 + (l & 15);
    unsigned short hi, lo;
    split_bf16(W2[k * HID2 + col], hi, lo);
    W2F[idx]         = hi;
    W2F[32768 + idx] = lo;
  } else if (gid < 32768 + 65536) {
    const int idx = gid - 32768;
    const int i  = idx & 7;
    const int l  = (idx >> 3) & 63;
    const int nf = (idx >> 9) & 31;
    const int ks = idx >> 14;
    const int k = ks * 32 + (l >> 4) * 8 + i;
    const int n = nf * 16 + (l & 15);
    const float v = (n < 256) ? W1[k * HID + n] : W1[(128 + k) * HID + (n - 256)];
    unsigned short hi, lo;
    split_bf16(v, hi, lo);
    W1F[idx]         = hi;
    W1F[65536 + idx] = lo;
  }
}

// ---------------------------------------------------------------------------
// pq_mfma: PQb[n][0:512] = bf16_rne( x[n] @ W1' + [b1, 0] )  (b1 folded into
// the P half). 3-term split MFMA. Block: 64 nodes x 256 cols (nhalf).
// ---------------------------------------------------------------------------
__global__ __launch_bounds__(256) void pq_mfma(
    const float* __restrict__ x, const unsigned short* __restrict__ W1F,
    const float* __restrict__ b1, unsigned short* __restrict__ PQb) {
  const int bid   = blockIdx.x;
  const int nhalf = bid & 1;
  const int n0    = (bid >> 1) * 64;
  const int t     = threadIdx.x;

  __shared__ __align__(16) unsigned short xhi[64 * 128];  // 16 KB swizzled
  __shared__ __align__(16) unsigned short xlo[64 * 128];  // 16 KB swizzled

#pragma unroll
  for (int rep = 0; rep < 8; ++rep) {
    const int flat = rep * 1024 + t * 4;
    const int row = flat >> 7, f0 = flat & 127;
    float4 v = make_float4(0.f, 0.f, 0.f, 0.f);
    if (n0 + row < NNODES)
      v = *reinterpret_cast<const float4*>(&x[(size_t)(n0 + row) * NFEAT + f0]);
    unsigned short h[4], l[4];
    split_bf16(v.x, h[0], l[0]); split_bf16(v.y, h[1], l[1]);
    split_bf16(v.z, h[2], l[2]); split_bf16(v.w, h[3], l[3]);
    const unsigned bt = (unsigned)(row * 256) +
                        (((unsigned)(2 * f0)) ^ (((unsigned)(row & 7)) << 4));
    *reinterpret_cast<uint2*>(reinterpret_cast<char*>(xhi) + bt) =
        make_uint2((unsigned)h[0] | ((unsigned)h[1] << 16),
                   (unsigned)h[2] | ((unsigned)h[3] << 16));
    *reinterpret_cast<uint2*>(reinterpret_cast<char*>(xlo) + bt) =
        make_uint2((unsigned)l[0] | ((unsigned)l[1] << 16),
                   (unsigned)l[2] | ((unsigned)l[3] << 16));
  }
  __syncthreads();

  const int wid = t >> 6, lane = t & 63;
  const int rg = wid >> 1, cg = wid & 1;
  const int lr = lane & 15, kc = lane >> 4;

  floatx4 acc[2][8];
#pragma unroll
  for (int mf = 0; mf < 2; ++mf)
#pragma unroll
    for (int nf = 0; nf < 8; ++nf) acc[mf][nf] = (floatx4)0.f;

#pragma unroll
  for (int ks = 0; ks < 4; ++ks) {
    short8 ah[2], al[2];
#pragma unroll
    for (int mf = 0; mf < 2; ++mf) {
      const int row = rg * 32 + mf * 16 + lr;
      const unsigned bt = (unsigned)(row * 256) +
                          (((unsigned)(ks * 64 + kc * 16)) ^ (((unsigned)(row & 7)) << 4));
      ah[mf] = *reinterpret_cast<const short8*>(reinterpret_cast<const char*>(xhi) + bt);
      al[mf] = *reinterpret_cast<const short8*>(reinterpret_cast<const char*>(xlo) + bt);
    }
#pragma unroll
    for (int nf = 0; nf < 8; ++nf) {
      const int nfg = nhalf * 16 + cg * 8 + nf;
      const size_t off = ((size_t)(ks * 32 + nfg) * 64 + lane) * 8;
      const short8 bh = *reinterpret_cast<const short8*>(W1F + off);
      const short8 bl = *reinterpret_cast<const short8*>(W1F + 65536 + off);
#pragma unroll
      for (int mf = 0; mf < 2; ++mf) {
        acc[mf][nf] = __builtin_amdgcn_mfma_f32_16x16x32_bf16(ah[mf], bh, acc[mf][nf], 0, 0, 0);
        acc[mf][nf] = __builtin_amdgcn_mfma_f32_16x16x32_bf16(ah[mf], bl, acc[mf][nf], 0, 0, 0);
        acc[mf][nf] = __builtin_amdgcn_mfma_f32_16x16x32_bf16(al[mf], bh, acc[mf][nf], 0, 0, 0);
      }
    }
  }

  // epilogue: +b1 on the P half (nhalf==0), RNE -> bf16, store.
  float bias[8];
#pragma unroll
  for (int nf = 0; nf < 8; ++nf)
    bias[nf] = (nhalf == 0) ? b1[cg * 128 + nf * 16 + lr] : 0.f;

#pragma unroll
  for (int mf = 0; mf < 2; ++mf)
#pragma unroll
    for (int nf = 0; nf < 8; ++nf)
#pragma unroll
      for (int r = 0; r < 4; ++r) {
        const int node = n0 + rg * 32 + mf * 16 + kc * 4 + r;
        const int col  = nhalf * 256 + cg * 128 + nf * 16 + lr;
        if (node < NNODES)
          PQb[(size_t)node * 512 + col] = bf16_rne(acc[mf][nf][r] + bias[nf]);
      }
}

// ---------------------------------------------------------------------------
// edge_mlp_mfma5: 512 threads / 8 waves, T=8 64-edge tiles per block.
//   Wave w owns output cols [16w,16w+16) (1 n-frag) for all 64 rows (4 mf);
//   its W2 B-fragments (8 ks x hi/lo = 64 VGPR) are loaded ONCE -> the MFMA
//   phase is pure LDS+MFMA (no vmem, no vmcnt coupling).
//   All 64 edge indices per wave preloaded in ONE load (lane = t*8+j);
//   readlane -> SGPR-base gather. Tile t+1's gathers issue before MFMA(t)
//   and stay in flight through it (T14 prefetch).
// ---------------------------------------------------------------------------
__global__ __launch_bounds__(512, 4) void edge_mlp_mfma5(
    const int* __restrict__ ei,
    const unsigned short* __restrict__ W2F, const float* __restrict__ b2,
    const float* __restrict__ W3, const float* __restrict__ b3,
    const unsigned short* __restrict__ PQb, float* __restrict__ out) {
  constexpr int T = 8;
  constexpr int NT_TOT = NEDGES / 64;  // 9375
  const int tid  = threadIdx.x;
  const int bid  = blockIdx.x;
  const int wid  = tid >> 6, lane = tid & 63;
  const int lr   = lane & 15, kc = lane >> 4;
  const int tile0 = bid * T;
  const int nt   = min(T, NT_TOT - tile0);

  __shared__ __align__(16) unsigned short h1s[64 * 256];  // 32 KB swizzled
  __shared__ float outs[8][64];                           // 2 KB

  // one load: all T tiles' indices for this wave (lane = t*8 + j)
  const int eidx = min(tile0 * 64 + wid * 8 + (lane >> 3) * 64 + (lane & 7),
                       NEDGES - 1);
  const int rvAll = ei[eidx];
  const int cvAll = ei[NEDGES + eidx];

  // W2 B-fragments resident (nfg = wid): 16 x short8 = 64 VGPR
  short8 Bh[8], Bl[8];
#pragma unroll
  for (int ks = 0; ks < 8; ++ks) {
    const unsigned off = (unsigned)(((ks * 8 + wid) * 64 + lane) * 8);
    Bh[ks] = *reinterpret_cast<const short8*>(W2F + off);
    Bl[ks] = *reinterpret_cast<const short8*>(W2F + 32768 + off);
  }
  const float w3v = W3[wid * 16 + lr];
  const float b2v = b2[wid * 16 + lr];
  const float b3v = b3[0];

  const char* PQc = reinterpret_cast<const char*>(PQb);
  const unsigned vo = (unsigned)(lane * 8);  // this lane's 8B of a 512B row

  // prologue: gather tile 0
  uint2 P[8], Q[8];
#pragma unroll
  for (int j = 0; j < 8; ++j) {
    const int r = __builtin_amdgcn_readlane(rvAll, j);
    const int c = __builtin_amdgcn_readlane(cvAll, j);
    P[j] = *reinterpret_cast<const uint2*>(PQc + (size_t)r * 1024 + vo);
    Q[j] = *reinterpret_cast<const uint2*>(PQc + (size_t)c * 1024 + 512 + vo);
  }

  for (int t = 0; t < nt; ++t) {
    // ---- fuse + write h1s (waits on this tile's gathers only) ----
#pragma unroll
    for (int j = 0; j < 8; ++j) {
      const int el = wid * 8 + j;                      // el & 7 == j
      const unsigned bt = (unsigned)(el * 512) + (vo ^ ((unsigned)j << 4));
      *reinterpret_cast<uint2*>(reinterpret_cast<char*>(h1s) + bt) =
          make_uint2(fuse2(P[j].x, Q[j].x), fuse2(P[j].y, Q[j].y));
    }
    __syncthreads();

    // ---- issue next tile's gathers (in flight through the MFMA phase) ----
    if (t + 1 < nt) {
      const int base = (t + 1) * 8;
#pragma unroll
      for (int j = 0; j < 8; ++j) {
        const int r = __builtin_amdgcn_readlane(rvAll, base + j);
        const int c = __builtin_amdgcn_readlane(cvAll, base + j);
        P[j] = *reinterpret_cast<const uint2*>(PQc + (size_t)r * 1024 + vo);
        Q[j] = *reinterpret_cast<const uint2*>(PQc + (size_t)c * 1024 + 512 + vo);
      }
    }

    // ---- MFMA: pure LDS + matrix pipe ----
    floatx4 acc[4];
#pragma unroll
    for (int mf = 0; mf < 4; ++mf) acc[mf] = (floatx4)0.f;
#pragma unroll
    for (int ks = 0; ks < 8; ++ks) {
#pragma unroll
      for (int mf = 0; mf < 4; ++mf) {
        const int row = mf * 16 + lr;
        const unsigned bt = (unsigned)(row * 512) +
            (((unsigned)(ks * 64 + kc * 16)) ^ (((unsigned)(row & 7)) << 4));
        const short8 ah = *reinterpret_cast<const short8*>(
            reinterpret_cast<const char*>(h1s) + bt);
        acc[mf] = __builtin_amdgcn_mfma_f32_16x16x32_bf16(ah, Bh[ks], acc[mf], 0, 0, 0);
        acc[mf] = __builtin_amdgcn_mfma_f32_16x16x32_bf16(ah, Bl[ks], acc[mf], 0, 0, 0);
      }
    }

    // ---- epilogue: leaky_relu(C+b2)*W3, reduce over the 16 col-lanes ----
#pragma unroll
    for (int mf = 0; mf < 4; ++mf) {
#pragma unroll
      for (int r = 0; r < 4; ++r) {
        float h = acc[mf][r] + b2v;
        h = (h > 0.f) ? h : LEAKY * h;
        float p = h * w3v;
#pragma unroll
        for (int m = 1; m <= 8; m <<= 1) p += __shfl_xor(p, m, 64);
        if (lr == 0) outs[wid][mf * 16 + kc * 4 + r] = p;
      }
    }
    __syncthreads();

    if (tid < 64) {
      float s = b3v;
#pragma unroll
      for (int w = 0; w < 8; ++w) s += outs[w][tid];
      out[(tile0 + t) * 64 + tid] = s;
    }
  }
}

// ---------------------------------------------------------------------------
// Fallback (ws too small): direct fp32 path, 32-edge tiles.
// ---------------------------------------------------------------------------
__global__ __launch_bounds__(256) void edge_mlp_direct(
    const float* __restrict__ x, const int* __restrict__ ei,
    const float* __restrict__ W1, const float* __restrict__ b1,
    const float* __restrict__ W2, const float* __restrict__ b2,
    const float* __restrict__ W3, const float* __restrict__ b3,
    float* __restrict__ out) {
  const int t  = threadIdx.x;
  const int e0 = blockIdx.x * 32;

  __shared__ __align__(16) float h1f[32 * HID];
  __shared__ int eidx[2][32];

  if (t < 32)      eidx[0][t]      = ei[e0 + t];
  else if (t < 64) eidx[1][t - 32] = ei[NEDGES + e0 + (t - 32)];
  __syncthreads();

  const float b1r = b1[t];
  __shared__ float xr[32][128];
  __shared__ float xc[32][128];
  for (int idx = t; idx < 32 * 128; idx += 256) {
    const int e = idx >> 7, f = idx & 127;
    xr[e][f] = x[(size_t)eidx[0][e] * NFEAT + f];
    xc[e][f] = x[(size_t)eidx[1][e] * NFEAT + f];
  }
  __syncthreads();
  float s[32];
#pragma unroll
  for (int e = 0; e < 32; ++e) s[e] = b1r;
  for (int f = 0; f < 128; ++f) {
    const float wr = W1[f * HID + t];
    const float wb = W1[(128 + f) * HID + t];
#pragma unroll
    for (int e = 0; e < 32; ++e)
      s[e] = fmaf(xr[e][f], wr, fmaf(xc[e][f], wb, s[e]));
  }
#pragma unroll
  for (int e = 0; e < 32; ++e) h1f[e * HID + t] = fmaxf(s[e], 0.f);
  __syncthreads();

  const int tr = t >> 5;
  const int tc = t & 31;
  float acc[4][4];
#pragma unroll
  for (int i = 0; i < 4; ++i)
#pragma unroll
    for (int j = 0; j < 4; ++j) acc[i][j] = 0.f;

  const float4* __restrict__ W2v = reinterpret_cast<const float4*>(W2);
  const float4* __restrict__ h1v = reinterpret_cast<const float4*>(h1f);
  for (int k = 0; k < HID; k += 4) {
    float4 a[4];
#pragma unroll
    for (int i = 0; i < 4; ++i) a[i] = h1v[((4 * tr + i) * HID + k) >> 2];
    float4 b[4];
#pragma unroll
    for (int kk = 0; kk < 4; ++kk) b[kk] = W2v[(k + kk) * 32 + tc];
#pragma unroll
    for (int i = 0; i < 4; ++i) {
      const float* av = reinterpret_cast<const float*>(&a[i]);
#pragma unroll
      for (int kk = 0; kk < 4; ++kk) {
        const float* bv = reinterpret_cast<const float*>(&b[kk]);
#pragma unroll
        for (int j = 0; j < 4; ++j) acc[i][j] = fmaf(av[kk], bv[j], acc[i][j]);
      }
    }
  }

  float w3r[4], b2r[4];
#pragma unroll
  for (int j = 0; j < 4; ++j) {
    w3r[j] = W3[4 * tc + j];
    b2r[j] = b2[4 * tc + j];
  }
  const float b3v = b3[0];
  float partial[4];
#pragma unroll
  for (int i = 0; i < 4; ++i) {
    float sp = 0.f;
#pragma unroll
    for (int j = 0; j < 4; ++j) {
      float h = acc[i][j] + b2r[j];
      h = (h > 0.f) ? h : LEAKY * h;
      sp = fmaf(h, w3r[j], sp);
    }
    partial[i] = sp;
  }
#pragma unroll
  for (int m = 16; m >= 1; m >>= 1)
#pragma unroll
    for (int i = 0; i < 4; ++i) partial[i] += __shfl_xor(partial[i], m, 32);
  if (tc == 0) {
#pragma unroll
    for (int i = 0; i < 4; ++i) out[e0 + 4 * tr + i] = partial[i] + b3v;
  }
}

extern "C" void kernel_launch(void* const* d_in, const int* in_sizes, int n_in,
                              void* d_out, int out_size, void* d_ws, size_t ws_size,
                              hipStream_t stream) {
  const float* x  = (const float*)d_in[0];
  const int*   ei = (const int*)d_in[1];
  const float* W1 = (const float*)d_in[2];
  const float* b1 = (const float*)d_in[3];
  const float* W2 = (const float*)d_in[4];
  const float* b2 = (const float*)d_in[5];
  const float* W3 = (const float*)d_in[6];
  const float* b3 = (const float*)d_in[7];
  float* out = (float*)d_out;

  const size_t pqb_bytes = (size_t)NNODES * 512 * 2;      // 51,200,000
  const size_t w2f_bytes = (size_t)2 * 32768 * 2;         // 131,072
  const size_t w1f_bytes = (size_t)2 * 65536 * 2;         // 262,144
  const size_t need = pqb_bytes + w2f_bytes + w1f_bytes;

  if (ws_size >= need) {
    unsigned short* PQb = (unsigned short*)d_ws;
    unsigned short* W2F = (unsigned short*)((char*)d_ws + pqb_bytes);
    unsigned short* W1F = (unsigned short*)((char*)d_ws + pqb_bytes + w2f_bytes);

    pack_w<<<(32768 + 65536 + 255) / 256, 256, 0, stream>>>(W2, W1, W2F, W1F);
    const int pq_blocks = ((NNODES + 63) / 64) * 2;       // 1564
    pq_mfma<<<pq_blocks, 256, 0, stream>>>(x, W1F, b1, PQb);
    const int n_tiles = NEDGES / 64;                      // 9375
    const int grid = (n_tiles + 7) / 8;                   // 1172
    edge_mlp_mfma5<<<grid, 512, 0, stream>>>(ei, W2F, b2, W3, b3, PQb, out);
  } else {
    edge_mlp_direct<<<NEDGES / 32, 256, 0, stream>>>(x, ei, W1, b1, W2, b2, W3, b3, out);
  }
}

// Round 7
// 191.028 us; speedup vs baseline: 1.5839x; 1.5839x over previous
//
#include <hip/hip_runtime.h>
#include <hip/hip_bf16.h>

#define NNODES 50000
#define NFEAT  128
#define NEDGES 600000
#define HID    256
#define HID2   128
#define LEAKY  0.01f

typedef __attribute__((ext_vector_type(8))) short short8;
typedef __attribute__((ext_vector_type(4))) float floatx4;

// Truncation split: x ~= hi + lo (each bf16), residual ~2^-17 rel.
__device__ __forceinline__ void split_bf16(float x, unsigned short& hi, unsigned short& lo) {
  union { float f; unsigned u; } a; a.f = x;
  hi = (unsigned short)(a.u >> 16);
  union { float f; unsigned u; } h; h.u = (unsigned)hi << 16;
  union { float f; unsigned u; } r; r.f = x - h.f;
  lo = (unsigned short)(r.u >> 16);
}

// RNE fp32 -> bf16 (scalar)
__device__ __forceinline__ unsigned short bf16_rne(float x) {
  union { float f; unsigned u; } a; a.f = x;
  unsigned r = a.u + 0x7FFFu + ((a.u >> 16) & 1u);
  return (unsigned short)(r >> 16);
}

// RNE pack two fp32 -> u32 of 2 bf16 (a in low half) — emits cvt_pk.
__device__ __forceinline__ unsigned pack2_rne(float a, float b) {
  __hip_bfloat162 h = __float22bfloat162_rn(make_float2(a, b));
  unsigned u; __builtin_memcpy(&u, &h, 4); return u;
}

__device__ __forceinline__ float ubits2f(unsigned u) {
  union { unsigned u; float f; } c; c.u = u; return c.f;
}

// relu(P+Q) for a packed bf16 pair (b1 pre-folded into P), repacked RNE.
__device__ __forceinline__ unsigned fuse2(unsigned pw, unsigned qw) {
  const float a0 = ubits2f(pw << 16), a1 = ubits2f(pw & 0xFFFF0000u);
  const float c0 = ubits2f(qw << 16), c1 = ubits2f(qw & 0xFFFF0000u);
  return pack2_rne(fmaxf(a0 + c0, 0.f), fmaxf(a1 + c1, 0.f));
}

// ---------------------------------------------------------------------------
// pack_w: merged W2 + W1 packing into MFMA B-frag order, bf16 hi/lo planes.
// W2F[((ks*8+nf)*64+l)*8+i]:  k=ks*32+(l>>4)*8+i, col=nf*16+(l&15)   (32768/plane)
// W1F[((ks*32+nf)*64+l)*8+i]: k=ks*32+(l>>4)*8+i, n=nf*16+(l&15)     (65536/plane)
//   W1'[k][n] = n<256 ? W1[k][n] : W1[128+k][n-256]
// ---------------------------------------------------------------------------
__global__ __launch_bounds__(256) void pack_w(const float* __restrict__ W2,
                                              const float* __restrict__ W1,
                                              unsigned short* __restrict__ W2F,
                                              unsigned short* __restrict__ W1F) {
  const int gid = blockIdx.x * 256 + threadIdx.x;
  if (gid < 32768) {
    const int idx = gid;
    const int i  = idx & 7;
    const int l  = (idx >> 3) & 63;
    const int nf = (idx >> 9) & 7;
    const int ks = idx >> 12;
    const int k   = ks * 32 + (l >> 4) * 8 + i;
    const int col = nf * 16 + (l & 15);
    unsigned short hi, lo;
    split_bf16(W2[k * HID2 + col], hi, lo);
    W2F[idx]         = hi;
    W2F[32768 + idx] = lo;
  } else if (gid < 32768 + 65536) {
    const int idx = gid - 32768;
    const int i  = idx & 7;
    const int l  = (idx >> 3) & 63;
    const int nf = (idx >> 9) & 31;
    const int ks = idx >> 14;
    const int k = ks * 32 + (l >> 4) * 8 + i;
    const int n = nf * 16 + (l & 15);
    const float v = (n < 256) ? W1[k * HID + n] : W1[(128 + k) * HID + (n - 256)];
    unsigned short hi, lo;
    split_bf16(v, hi, lo);
    W1F[idx]         = hi;
    W1F[65536 + idx] = lo;
  }
}

// ---------------------------------------------------------------------------
// pq_mfma: Pb[n][0:256] = bf16_rne( x[n] @ W1'[:,0:256] + b1 )
//          Qb[n][0:256] = bf16_rne( x[n] @ W1'[:,256:512] )
// 3-term split MFMA. Block: 64 nodes x 256 cols (nhalf: 0->Pb, 1->Qb).
// Epilogue: stage output in LDS (reuse x buffers), store coalesced uint4.
// ---------------------------------------------------------------------------
__global__ __launch_bounds__(256) void pq_mfma(
    const float* __restrict__ x, const unsigned short* __restrict__ W1F,
    const float* __restrict__ b1,
    unsigned short* __restrict__ Pb, unsigned short* __restrict__ Qb) {
  const int bid   = blockIdx.x;
  const int nhalf = bid & 1;
  const int n0    = (bid >> 1) * 64;
  const int t     = threadIdx.x;

  __shared__ __align__(16) unsigned short sbuf[2][64 * 128];  // xhi/xlo, 32 KB
  unsigned short* xhi = sbuf[0];
  unsigned short* xlo = sbuf[1];

#pragma unroll
  for (int rep = 0; rep < 8; ++rep) {
    const int flat = rep * 1024 + t * 4;
    const int row = flat >> 7, f0 = flat & 127;
    float4 v = make_float4(0.f, 0.f, 0.f, 0.f);
    if (n0 + row < NNODES)
      v = *reinterpret_cast<const float4*>(&x[(size_t)(n0 + row) * NFEAT + f0]);
    unsigned short h[4], l[4];
    split_bf16(v.x, h[0], l[0]); split_bf16(v.y, h[1], l[1]);
    split_bf16(v.z, h[2], l[2]); split_bf16(v.w, h[3], l[3]);
    const unsigned bt = (unsigned)(row * 256) +
                        (((unsigned)(2 * f0)) ^ (((unsigned)(row & 7)) << 4));
    *reinterpret_cast<uint2*>(reinterpret_cast<char*>(xhi) + bt) =
        make_uint2((unsigned)h[0] | ((unsigned)h[1] << 16),
                   (unsigned)h[2] | ((unsigned)h[3] << 16));
    *reinterpret_cast<uint2*>(reinterpret_cast<char*>(xlo) + bt) =
        make_uint2((unsigned)l[0] | ((unsigned)l[1] << 16),
                   (unsigned)l[2] | ((unsigned)l[3] << 16));
  }
  __syncthreads();

  const int wid = t >> 6, lane = t & 63;
  const int rg = wid >> 1, cg = wid & 1;
  const int lr = lane & 15, kc = lane >> 4;

  floatx4 acc[2][8];
#pragma unroll
  for (int mf = 0; mf < 2; ++mf)
#pragma unroll
    for (int nf = 0; nf < 8; ++nf) acc[mf][nf] = (floatx4)0.f;

#pragma unroll
  for (int ks = 0; ks < 4; ++ks) {
    short8 ah[2], al[2];
#pragma unroll
    for (int mf = 0; mf < 2; ++mf) {
      const int row = rg * 32 + mf * 16 + lr;
      const unsigned bt = (unsigned)(row * 256) +
                          (((unsigned)(ks * 64 + kc * 16)) ^ (((unsigned)(row & 7)) << 4));
      ah[mf] = *reinterpret_cast<const short8*>(reinterpret_cast<const char*>(xhi) + bt);
      al[mf] = *reinterpret_cast<const short8*>(reinterpret_cast<const char*>(xlo) + bt);
    }
#pragma unroll
    for (int nf = 0; nf < 8; ++nf) {
      const int nfg = nhalf * 16 + cg * 8 + nf;
      const size_t off = ((size_t)(ks * 32 + nfg) * 64 + lane) * 8;
      const short8 bh = *reinterpret_cast<const short8*>(W1F + off);
      const short8 bl = *reinterpret_cast<const short8*>(W1F + 65536 + off);
#pragma unroll
      for (int mf = 0; mf < 2; ++mf) {
        acc[mf][nf] = __builtin_amdgcn_mfma_f32_16x16x32_bf16(ah[mf], bh, acc[mf][nf], 0, 0, 0);
        acc[mf][nf] = __builtin_amdgcn_mfma_f32_16x16x32_bf16(ah[mf], bl, acc[mf][nf], 0, 0, 0);
        acc[mf][nf] = __builtin_amdgcn_mfma_f32_16x16x32_bf16(al[mf], bh, acc[mf][nf], 0, 0, 0);
      }
    }
  }

  // bias: +b1 on the P half only
  float bias[8];
#pragma unroll
  for (int nf = 0; nf < 8; ++nf)
    bias[nf] = (nhalf == 0) ? b1[cg * 128 + nf * 16 + lr] : 0.f;

  // ---- stage tile output (64 x 256 bf16 = 32 KB) into reused LDS ----
  __syncthreads();  // all xhi/xlo reads done before overwrite
  unsigned short* stg = &sbuf[0][0];
#pragma unroll
  for (int mf = 0; mf < 2; ++mf)
#pragma unroll
    for (int nf = 0; nf < 8; ++nf)
#pragma unroll
      for (int r = 0; r < 4; ++r) {
        const int rl = rg * 32 + mf * 16 + kc * 4 + r;   // 0..63
        const int cl = cg * 128 + nf * 16 + lr;          // 0..255
        stg[rl * 256 + cl] = bf16_rne(acc[mf][nf][r] + bias[nf]);
      }
  __syncthreads();

  // ---- coalesced uint4 stores ----
  unsigned short* dst = (nhalf == 0) ? Pb : Qb;
#pragma unroll
  for (int rep = 0; rep < 8; ++rep) {
    const int i = rep * 256 + t;        // 0..2047
    const int row = i >> 5, colu = i & 31;
    if (n0 + row < NNODES)
      *reinterpret_cast<uint4*>(reinterpret_cast<char*>(dst) +
                                (size_t)(n0 + row) * 512 + colu * 16) =
          *reinterpret_cast<const uint4*>(reinterpret_cast<const char*>(stg) +
                                          row * 512 + colu * 16);
  }
}

// ---------------------------------------------------------------------------
// edge_mlp_mfma6: per 64-edge tile (R4 structure + paired-row uint4 gather).
//   gather: one uint4 wave-load serves 2 edges (lanes 0-31 / 32-63);
//           16 loads per wave instead of 32; b1 pre-folded into Pb.
//   GEMM:   C(64x128) = h1 @ W2, 2-term (Ah*Bh + Ah*Bl)
//   epi:    out[e] = leakyrelu(C+b2) @ W3 + b3
// ---------------------------------------------------------------------------
__global__ __launch_bounds__(256) void edge_mlp_mfma6(
    const int* __restrict__ ei,
    const unsigned short* __restrict__ W2F, const float* __restrict__ b2,
    const float* __restrict__ W3, const float* __restrict__ b3,
    const unsigned short* __restrict__ Pb, const unsigned short* __restrict__ Qb,
    float* __restrict__ out) {
  const int t  = threadIdx.x;
  const int e0 = blockIdx.x * 64;
  const int wid = t >> 6, lane = t & 63;

  __shared__ __align__(16) unsigned short h1s[64 * 256];  // 32 KB swizzled
  __shared__ float outs[4][64];

  // lanes 0-15 hold this wave's 16 edge indices (replicated)
  const int rv = ei[e0 + wid * 16 + (lane & 15)];
  const int cv = ei[NEDGES + e0 + wid * 16 + (lane & 15)];
  const int half = (lane >> 5) & 1;        // which edge of the pair
  const unsigned lo5 = (unsigned)(lane & 31);
  const char* Pc = reinterpret_cast<const char*>(Pb);
  const char* Qc = reinterpret_cast<const char*>(Qb);

  // ---- gather: 16 uint4 wave-loads, 2 edges per load ----
  uint4 Pv[8], Qv[8];
#pragma unroll
  for (int p = 0; p < 8; ++p) {
    const int rlo = __builtin_amdgcn_readlane(rv, 2 * p);
    const int rhi = __builtin_amdgcn_readlane(rv, 2 * p + 1);
    const int clo = __builtin_amdgcn_readlane(cv, 2 * p);
    const int chi = __builtin_amdgcn_readlane(cv, 2 * p + 1);
    const int rr = half ? rhi : rlo;
    const int cc = half ? chi : clo;
    Pv[p] = *reinterpret_cast<const uint4*>(Pc + (size_t)rr * 512 + lo5 * 16);
    Qv[p] = *reinterpret_cast<const uint4*>(Qc + (size_t)cc * 512 + lo5 * 16);
  }

  // ---- fuse: relu(P+Q) -> swizzled LDS (b128) ----
#pragma unroll
  for (int p = 0; p < 8; ++p) {
    const uint4 o = make_uint4(fuse2(Pv[p].x, Qv[p].x), fuse2(Pv[p].y, Qv[p].y),
                               fuse2(Pv[p].z, Qv[p].z), fuse2(Pv[p].w, Qv[p].w));
    const int e = wid * 16 + 2 * p + half;
    const unsigned bt = (unsigned)(e * 512) +
                        ((lo5 * 16) ^ (((unsigned)(e & 7)) << 4));
    *reinterpret_cast<uint4*>(reinterpret_cast<char*>(h1s) + bt) = o;
  }
  __syncthreads();

  // ---- MFMA: wave w -> cols [32w,32w+32) (2 nf), all 64 rows (4 mf) ----
  const int lr = lane & 15, kc = lane >> 4;

  floatx4 acc[4][2];
#pragma unroll
  for (int mf = 0; mf < 4; ++mf)
#pragma unroll
    for (int nf = 0; nf < 2; ++nf) acc[mf][nf] = (floatx4)0.f;

#pragma unroll
  for (int ks = 0; ks < 8; ++ks) {
    short8 ah[4];
#pragma unroll
    for (int mf = 0; mf < 4; ++mf) {
      const int row = mf * 16 + lr;
      const unsigned bt = (unsigned)(row * 512) +
                          (((unsigned)(ks * 64 + kc * 16)) ^ (((unsigned)(row & 7)) << 4));
      ah[mf] = *reinterpret_cast<const short8*>(reinterpret_cast<const char*>(h1s) + bt);
    }
    short8 bh[2], bl[2];
#pragma unroll
    for (int nf = 0; nf < 2; ++nf) {
      const int nfg = wid * 2 + nf;
      const unsigned off = (unsigned)(((ks * 8 + nfg) * 64 + lane) * 8);
      bh[nf] = *reinterpret_cast<const short8*>(W2F + off);
      bl[nf] = *reinterpret_cast<const short8*>(W2F + 32768 + off);
    }
#pragma unroll
    for (int mf = 0; mf < 4; ++mf)
#pragma unroll
      for (int nf = 0; nf < 2; ++nf) {
        acc[mf][nf] = __builtin_amdgcn_mfma_f32_16x16x32_bf16(ah[mf], bh[nf], acc[mf][nf], 0, 0, 0);
        acc[mf][nf] = __builtin_amdgcn_mfma_f32_16x16x32_bf16(ah[mf], bl[nf], acc[mf][nf], 0, 0, 0);
      }
  }

  // ---- epilogue: leaky_relu(C+b2) @ W3, reduce over 16 col-lanes ----
  float w3v[2], b2v[2];
#pragma unroll
  for (int nf = 0; nf < 2; ++nf) {
    const int col = wid * 32 + nf * 16 + lr;
    w3v[nf] = W3[col];
    b2v[nf] = b2[col];
  }

  float part[4][4];
#pragma unroll
  for (int mf = 0; mf < 4; ++mf)
#pragma unroll
    for (int r = 0; r < 4; ++r) {
      float s = 0.f;
#pragma unroll
      for (int nf = 0; nf < 2; ++nf) {
        float h = acc[mf][nf][r] + b2v[nf];
        h = (h > 0.f) ? h : LEAKY * h;
        s = fmaf(h, w3v[nf], s);
      }
      part[mf][r] = s;
    }

#pragma unroll
  for (int m = 1; m <= 8; m <<= 1)
#pragma unroll
    for (int mf = 0; mf < 4; ++mf)
#pragma unroll
      for (int r = 0; r < 4; ++r) part[mf][r] += __shfl_xor(part[mf][r], m, 64);

  if (lr == 0) {
#pragma unroll
    for (int mf = 0; mf < 4; ++mf)
#pragma unroll
      for (int r = 0; r < 4; ++r) outs[wid][mf * 16 + kc * 4 + r] = part[mf][r];
  }
  __syncthreads();

  if (t < 64) {
    out[e0 + t] = outs[0][t] + outs[1][t] + outs[2][t] + outs[3][t] + b3[0];
  }
}

// ---------------------------------------------------------------------------
// Fallback (ws too small): direct fp32 path, 32-edge tiles.
// ---------------------------------------------------------------------------
__global__ __launch_bounds__(256) void edge_mlp_direct(
    const float* __restrict__ x, const int* __restrict__ ei,
    const float* __restrict__ W1, const float* __restrict__ b1,
    const float* __restrict__ W2, const float* __restrict__ b2,
    const float* __restrict__ W3, const float* __restrict__ b3,
    float* __restrict__ out) {
  const int t  = threadIdx.x;
  const int e0 = blockIdx.x * 32;

  __shared__ __align__(16) float h1f[32 * HID];
  __shared__ int eidx[2][32];

  if (t < 32)      eidx[0][t]      = ei[e0 + t];
  else if (t < 64) eidx[1][t - 32] = ei[NEDGES + e0 + (t - 32)];
  __syncthreads();

  const float b1r = b1[t];
  __shared__ float xr[32][128];
  __shared__ float xc[32][128];
  for (int idx = t; idx < 32 * 128; idx += 256) {
    const int e = idx >> 7, f = idx & 127;
    xr[e][f] = x[(size_t)eidx[0][e] * NFEAT + f];
    xc[e][f] = x[(size_t)eidx[1][e] * NFEAT + f];
  }
  __syncthreads();
  float s[32];
#pragma unroll
  for (int e = 0; e < 32; ++e) s[e] = b1r;
  for (int f = 0; f < 128; ++f) {
    const float wr = W1[f * HID + t];
    const float wb = W1[(128 + f) * HID + t];
#pragma unroll
    for (int e = 0; e < 32; ++e)
      s[e] = fmaf(xr[e][f], wr, fmaf(xc[e][f], wb, s[e]));
  }
#pragma unroll
  for (int e = 0; e < 32; ++e) h1f[e * HID + t] = fmaxf(s[e], 0.f);
  __syncthreads();

  const int tr = t >> 5;
  const int tc = t & 31;
  float acc[4][4];
#pragma unroll
  for (int i = 0; i < 4; ++i)
#pragma unroll
    for (int j = 0; j < 4; ++j) acc[i][j] = 0.f;

  const float4* __restrict__ W2v = reinterpret_cast<const float4*>(W2);
  const float4* __restrict__ h1v = reinterpret_cast<const float4*>(h1f);
  for (int k = 0; k < HID; k += 4) {
    float4 a[4];
#pragma unroll
    for (int i = 0; i < 4; ++i) a[i] = h1v[((4 * tr + i) * HID + k) >> 2];
    float4 b[4];
#pragma unroll
    for (int kk = 0; kk < 4; ++kk) b[kk] = W2v[(k + kk) * 32 + tc];
#pragma unroll
    for (int i = 0; i < 4; ++i) {
      const float* av = reinterpret_cast<const float*>(&a[i]);
#pragma unroll
      for (int kk = 0; kk < 4; ++kk) {
        const float* bv = reinterpret_cast<const float*>(&b[kk]);
#pragma unroll
        for (int j = 0; j < 4; ++j) acc[i][j] = fmaf(av[kk], bv[j], acc[i][j]);
      }
    }
  }

  float w3r[4], b2r[4];
#pragma unroll
  for (int j = 0; j < 4; ++j) {
    w3r[j] = W3[4 * tc + j];
    b2r[j] = b2[4 * tc + j];
  }
  const float b3v = b3[0];
  float partial[4];
#pragma unroll
  for (int i = 0; i < 4; ++i) {
    float sp = 0.f;
#pragma unroll
    for (int j = 0; j < 4; ++j) {
      float h = acc[i][j] + b2r[j];
      h = (h > 0.f) ? h : LEAKY * h;
      sp = fmaf(h, w3r[j], sp);
    }
    partial[i] = sp;
  }
#pragma unroll
  for (int m = 16; m >= 1; m >>= 1)
#pragma unroll
    for (int i = 0; i < 4; ++i) partial[i] += __shfl_xor(partial[i], m, 32);
  if (tc == 0) {
#pragma unroll
    for (int i = 0; i < 4; ++i) out[e0 + 4 * tr + i] = partial[i] + b3v;
  }
}

extern "C" void kernel_launch(void* const* d_in, const int* in_sizes, int n_in,
                              void* d_out, int out_size, void* d_ws, size_t ws_size,
                              hipStream_t stream) {
  const float* x  = (const float*)d_in[0];
  const int*   ei = (const int*)d_in[1];
  const float* W1 = (const float*)d_in[2];
  const float* b1 = (const float*)d_in[3];
  const float* W2 = (const float*)d_in[4];
  const float* b2 = (const float*)d_in[5];
  const float* W3 = (const float*)d_in[6];
  const float* b3 = (const float*)d_in[7];
  float* out = (float*)d_out;

  const size_t p_bytes   = (size_t)NNODES * 256 * 2;      // 25,600,000
  const size_t w2f_bytes = (size_t)2 * 32768 * 2;         // 131,072
  const size_t w1f_bytes = (size_t)2 * 65536 * 2;         // 262,144
  const size_t need = 2 * p_bytes + w2f_bytes + w1f_bytes;

  if (ws_size >= need) {
    unsigned short* Pb  = (unsigned short*)d_ws;
    unsigned short* Qb  = (unsigned short*)((char*)d_ws + p_bytes);
    unsigned short* W2F = (unsigned short*)((char*)d_ws + 2 * p_bytes);
    unsigned short* W1F = (unsigned short*)((char*)d_ws + 2 * p_bytes + w2f_bytes);

    pack_w<<<(32768 + 65536 + 255) / 256, 256, 0, stream>>>(W2, W1, W2F, W1F);
    const int pq_blocks = ((NNODES + 63) / 64) * 2;       // 1564
    pq_mfma<<<pq_blocks, 256, 0, stream>>>(x, W1F, b1, Pb, Qb);
    edge_mlp_mfma6<<<NEDGES / 64, 256, 0, stream>>>(ei, W2F, b2, W3, b3, Pb, Qb, out);
  } else {
    edge_mlp_direct<<<NEDGES / 32, 256, 0, stream>>>(x, ei, W1, b1, W2, b2, W3, b3, out);
  }
}